// Round 5
// baseline (1597.846 us; speedup 1.0000x reference)
//
#include <hip/hip_runtime.h>
#include <hip/hip_bf16.h>
#include <math.h>

// Problem constants: B=32, U=4096, K=4, N=2, K2=2, STRIDE=2048, UN=2048
// ws: (2, 4, 2048, 8192) f32 = 512 MB  -> the traffic floor
// GEMM per j: (32 x 8192) @ (8192 x 8192), f32 vector-FMA (no fp32 MFMA on CDNA4)
//
// d_out layout (flat, return order):
//   x_out  [0,      131072)   (32,4096)
//   new_hs [131072, 393216)   (2,2,32,2048)
//   new_c  [393216, 917504)   (2,4,32,2048)
//
// d_ws layout:
//   in_t    at byte 0    : 2*8192*32 f32 = 2 MB       (in_t[j][k][b])
//   partial at byte 2 MB : 2*16*32*8192 f32 = 33.5 MB (partial[j][s][b][f])

#define IN_T_ELEMS (2 * 8192 * 32)
#define NSPLIT 16

__global__ __launch_bounds__(256) void transpose_in(const float* __restrict__ x,
                                                    const float* __restrict__ hs,
                                                    float* __restrict__ in_t) {
    int tid = blockIdx.x * 256 + threadIdx.x;   // [0, 524288)
    int b   = tid & 31;
    int kkd = (tid >> 5) & 8191;
    int j   = tid >> 18;
    float v;
    if (kkd < 4096) {
        v = x[b * 4096 + kkd];                       // x_chunks[b][kk][d] = x[b][kkd]
    } else {
        int kk = kkd >> 11;                          // 2 or 3
        int d  = kkd & 2047;
        v = hs[((j * 2 + (kk - 2)) * 32 + b) * 2048 + d];   // hs (2,2,32,2048)
    }
    in_t[tid] = v;
}

__device__ __forceinline__ void fma_row(float acc[8][4], float4 a0, float4 a1, float4 wv) {
    acc[0][0] = fmaf(a0.x, wv.x, acc[0][0]);
    acc[0][1] = fmaf(a0.x, wv.y, acc[0][1]);
    acc[0][2] = fmaf(a0.x, wv.z, acc[0][2]);
    acc[0][3] = fmaf(a0.x, wv.w, acc[0][3]);
    acc[1][0] = fmaf(a0.y, wv.x, acc[1][0]);
    acc[1][1] = fmaf(a0.y, wv.y, acc[1][1]);
    acc[1][2] = fmaf(a0.y, wv.z, acc[1][2]);
    acc[1][3] = fmaf(a0.y, wv.w, acc[1][3]);
    acc[2][0] = fmaf(a0.z, wv.x, acc[2][0]);
    acc[2][1] = fmaf(a0.z, wv.y, acc[2][1]);
    acc[2][2] = fmaf(a0.z, wv.z, acc[2][2]);
    acc[2][3] = fmaf(a0.z, wv.w, acc[2][3]);
    acc[3][0] = fmaf(a0.w, wv.x, acc[3][0]);
    acc[3][1] = fmaf(a0.w, wv.y, acc[3][1]);
    acc[3][2] = fmaf(a0.w, wv.z, acc[3][2]);
    acc[3][3] = fmaf(a0.w, wv.w, acc[3][3]);
    acc[4][0] = fmaf(a1.x, wv.x, acc[4][0]);
    acc[4][1] = fmaf(a1.x, wv.y, acc[4][1]);
    acc[4][2] = fmaf(a1.x, wv.z, acc[4][2]);
    acc[4][3] = fmaf(a1.x, wv.w, acc[4][3]);
    acc[5][0] = fmaf(a1.y, wv.x, acc[5][0]);
    acc[5][1] = fmaf(a1.y, wv.y, acc[5][1]);
    acc[5][2] = fmaf(a1.y, wv.z, acc[5][2]);
    acc[5][3] = fmaf(a1.y, wv.w, acc[5][3]);
    acc[6][0] = fmaf(a1.z, wv.x, acc[6][0]);
    acc[6][1] = fmaf(a1.z, wv.y, acc[6][1]);
    acc[6][2] = fmaf(a1.z, wv.z, acc[6][2]);
    acc[6][3] = fmaf(a1.z, wv.w, acc[6][3]);
    acc[7][0] = fmaf(a1.w, wv.x, acc[7][0]);
    acc[7][1] = fmaf(a1.w, wv.y, acc[7][1]);
    acc[7][2] = fmaf(a1.w, wv.z, acc[7][2]);
    acc[7][3] = fmaf(a1.w, wv.w, acc[7][3]);
}

// Grid: 1024 blocks = 2 (j) x 32 (f-tile of 256) x 16 (K-chunk s). Block = 256 (4 waves),
// 4 blocks/CU (LDS 36 KB). Wave w owns batches [w*8, w*8+8); lane owns 4 consecutive f.
// BOTH operands staged through double-buffered LDS in 16-row stages:
//   wtile[2][16][256] (ws, 16 KB/stage) + itile[2][16][32] (in_t, 2 KB/stage).
// Reg-staged issue-early / write-late: stage t+2's global loads issue right after the
// barrier and are consumed (ds_write) a full compute phase (~1100 cyc) later -> HBM
// latency fully hidden without deep register pipelines. One __syncthreads per stage.
// Compute: ws via contiguous ds_read_b128 (conflict-free), in_t via uniform broadcast.
__global__ __launch_bounds__(256, 4) void gemm_partial(const float* __restrict__ in_t,
                                                       const float* __restrict__ wsm,
                                                       float* __restrict__ partial) {
    __shared__ float wtile[2][16][256];   // 32 KB
    __shared__ float itile[2][16][32];    //  4 KB

    int lin = blockIdx.x;
    int s   = lin & (NSPLIT - 1);
    int ft  = (lin >> 4) & 31;
    int j   = lin >> 9;
    int w    = __builtin_amdgcn_readfirstlane((int)(threadIdx.x >> 6));
    int lane = threadIdx.x & 63;
    int f0   = ft * 256 + lane * 4;
    int k0   = s * 512;

    // per-lane global sources for this wave's staging share
    const float* __restrict__ wsrc = wsm + ((size_t)j * 8192 + k0 + w) * 8192 + f0;
    const float* __restrict__ isrc = in_t + (size_t)(j * 8192 + k0) * 32 + w * 256 + lane * 4;

    float4 sw0, sw1, sw2, sw3, si;

    auto stage_load = [&](int t) {        // issue-early: global -> regs
        const float* p = wsrc + (size_t)t * 16 * 8192;
        sw0 = *(const float4*)(p);
        sw1 = *(const float4*)(p + (size_t)4 * 8192);
        sw2 = *(const float4*)(p + (size_t)8 * 8192);
        sw3 = *(const float4*)(p + (size_t)12 * 8192);
        if (w < 2) si = *(const float4*)(isrc + t * 512);
    };
    auto stage_write = [&](int t) {       // write-late: regs -> LDS buf (t&1)
        int buf = t & 1;
        *(float4*)&wtile[buf][w +  0][lane * 4] = sw0;
        *(float4*)&wtile[buf][w +  4][lane * 4] = sw1;
        *(float4*)&wtile[buf][w +  8][lane * 4] = sw2;
        *(float4*)&wtile[buf][w + 12][lane * 4] = sw3;
        if (w < 2) *(float4*)(&itile[buf][0][0] + w * 256 + lane * 4) = si;
    };

    float acc[8][4];
#pragma unroll
    for (int b = 0; b < 8; ++b)
#pragma unroll
        for (int q = 0; q < 4; ++q) acc[b][q] = 0.f;

    // prologue: stage 0 resident, stage 1 in flight
    stage_load(0);
    stage_write(0);
    __syncthreads();
    stage_load(1);

    int w8 = w * 8;
    int l4 = lane * 4;
    for (int t = 0; t < 32; ++t) {
        const float(*wt)[256] = wtile[t & 1];
        const float(*it)[32]  = itile[t & 1];
#pragma unroll
        for (int r = 0; r < 16; ++r) {
            float4 wv = *(const float4*)&wt[r][l4];
            float4 a0 = *(const float4*)&it[r][w8];
            float4 a1 = *(const float4*)&it[r][w8 + 4];
            fma_row(acc, a0, a1, wv);
        }
        if (t + 1 < 32) stage_write(t + 1);   // consumes regs loaded last iter
        __syncthreads();
        if (t + 2 < 32) stage_load(t + 2);    // in flight across next compute phase
    }

    // partial[j][s][b][f]: coalesced float4 stores
    size_t pbase = ((size_t)((j * NSPLIT + s) * 32 + w8)) * 8192 + f0;
#pragma unroll
    for (int b = 0; b < 8; ++b)
        *(float4*)(partial + pbase + (size_t)b * 8192) = *(const float4*)acc[b];
}

__device__ __forceinline__ float sigmoidf_(float v) { return 1.f / (1.f + expf(-v)); }

// 131072 threads: tid -> (j, b, un)
__global__ __launch_bounds__(256) void epilogue(const float* __restrict__ partial,
                                                const float* __restrict__ cs,
                                                float* __restrict__ out) {
    int tid = blockIdx.x * 256 + threadIdx.x;
    int un  = tid & 2047;
    int b   = (tid >> 11) & 31;
    int j   = tid >> 16;

    float g4[4];
#pragma unroll
    for (int gate = 0; gate < 4; ++gate) {
        int f = gate * 2048 + un;
        float sum = 0.f;
#pragma unroll
        for (int s = 0; s < NSPLIT; ++s)
            sum += partial[((size_t)((j * NSPLIT + s) * 32 + b)) * 8192 + f];
        g4[gate] = sum;
    }
    float iv = sigmoidf_(g4[0]);
    float fv = sigmoidf_(g4[1]);
    float gv = tanhf(g4[2]);
    float ov = sigmoidf_(g4[3]);
    float ig = iv * gv;

#pragma unroll
    for (int kk = 0; kk < 4; ++kk) {
        float c_old = cs[((j * 4 + kk) * 32 + b) * 2048 + un];
        float c_new = fv * c_old + ig;
        float h     = ov * tanhf(c_new);
        out[393216 + ((j * 4 + kk) * 32 + b) * 2048 + un] = c_new;   // new_c
        if (kk == 0) {
            out[b * 4096 + j * 2048 + un] = h;                       // x_out
        }
        if (kk == j + 2) {
            // new_hs[jj][j][b][un] = h for jj in {0,1}
            out[131072 + ((0 * 2 + j) * 32 + b) * 2048 + un] = h;
            out[131072 + ((1 * 2 + j) * 32 + b) * 2048 + un] = h;
        }
    }
}

extern "C" void kernel_launch(void* const* d_in, const int* in_sizes, int n_in,
                              void* d_out, int out_size, void* d_ws, size_t ws_size,
                              hipStream_t stream) {
    const float* x   = (const float*)d_in[0];
    const float* hs  = (const float*)d_in[1];
    const float* cs  = (const float*)d_in[2];
    const float* wsm = (const float*)d_in[3];
    float* out = (float*)d_out;

    float* in_t    = (float*)d_ws;                                    // 2 MB
    float* partial = (float*)((char*)d_ws + (size_t)IN_T_ELEMS * 4);  // 33.5 MB

    transpose_in<<<524288 / 256, 256, 0, stream>>>(x, hs, in_t);
    gemm_partial<<<1024, 256, 0, stream>>>(in_t, wsm, partial);
    epilogue<<<131072 / 256, 256, 0, stream>>>(partial, cs, out);
}

// Round 6
// 151.039 us; speedup vs baseline: 10.5790x; 10.5790x over previous
//
#include <hip/hip_runtime.h>
#include <hip/hip_bf16.h>
#include <math.h>

// Problem constants: B=32, U=4096, K=4, N=2, K2=2, STRIDE=2048, UN=2048
// ws: (2, 4, 2048, 8192) f32 = 512 MB  -> the traffic floor
// GEMM per j: (32 x 8192) @ (8192 x 8192), f32 vector-FMA (no fp32 MFMA on CDNA4)
//
// d_out layout (flat, return order):
//   x_out  [0,      131072)   (32,4096)
//   new_hs [131072, 393216)   (2,2,32,2048)
//   new_c  [393216, 917504)   (2,4,32,2048)
//
// d_ws layout:
//   in_t    at byte 0    : 2*8192*32 f32 = 2 MB       (in_t[j][k][b])
//   partial at byte 2 MB : 2*16*32*8192 f32 = 33.5 MB (partial[j][s][b][f])

#define IN_T_ELEMS (2 * 8192 * 32)
#define NSPLIT 16

__global__ __launch_bounds__(256) void transpose_in(const float* __restrict__ x,
                                                    const float* __restrict__ hs,
                                                    float* __restrict__ in_t) {
    int tid = blockIdx.x * 256 + threadIdx.x;   // [0, 524288)
    int b   = tid & 31;
    int kkd = (tid >> 5) & 8191;
    int j   = tid >> 18;
    float v;
    if (kkd < 4096) {
        v = x[b * 4096 + kkd];                       // x_chunks[b][kk][d] = x[b][kkd]
    } else {
        int kk = kkd >> 11;                          // 2 or 3
        int d  = kkd & 2047;
        v = hs[((j * 2 + (kk - 2)) * 32 + b) * 2048 + d];   // hs (2,2,32,2048)
    }
    in_t[tid] = v;
}

__device__ __forceinline__ void fma_row(float acc[8][4], float4 a0, float4 a1, float4 wv) {
    acc[0][0] = fmaf(a0.x, wv.x, acc[0][0]);
    acc[0][1] = fmaf(a0.x, wv.y, acc[0][1]);
    acc[0][2] = fmaf(a0.x, wv.z, acc[0][2]);
    acc[0][3] = fmaf(a0.x, wv.w, acc[0][3]);
    acc[1][0] = fmaf(a0.y, wv.x, acc[1][0]);
    acc[1][1] = fmaf(a0.y, wv.y, acc[1][1]);
    acc[1][2] = fmaf(a0.y, wv.z, acc[1][2]);
    acc[1][3] = fmaf(a0.y, wv.w, acc[1][3]);
    acc[2][0] = fmaf(a0.z, wv.x, acc[2][0]);
    acc[2][1] = fmaf(a0.z, wv.y, acc[2][1]);
    acc[2][2] = fmaf(a0.z, wv.z, acc[2][2]);
    acc[2][3] = fmaf(a0.z, wv.w, acc[2][3]);
    acc[3][0] = fmaf(a0.w, wv.x, acc[3][0]);
    acc[3][1] = fmaf(a0.w, wv.y, acc[3][1]);
    acc[3][2] = fmaf(a0.w, wv.z, acc[3][2]);
    acc[3][3] = fmaf(a0.w, wv.w, acc[3][3]);
    acc[4][0] = fmaf(a1.x, wv.x, acc[4][0]);
    acc[4][1] = fmaf(a1.x, wv.y, acc[4][1]);
    acc[4][2] = fmaf(a1.x, wv.z, acc[4][2]);
    acc[4][3] = fmaf(a1.x, wv.w, acc[4][3]);
    acc[5][0] = fmaf(a1.y, wv.x, acc[5][0]);
    acc[5][1] = fmaf(a1.y, wv.y, acc[5][1]);
    acc[5][2] = fmaf(a1.y, wv.z, acc[5][2]);
    acc[5][3] = fmaf(a1.y, wv.w, acc[5][3]);
    acc[6][0] = fmaf(a1.z, wv.x, acc[6][0]);
    acc[6][1] = fmaf(a1.z, wv.y, acc[6][1]);
    acc[6][2] = fmaf(a1.z, wv.z, acc[6][2]);
    acc[6][3] = fmaf(a1.z, wv.w, acc[6][3]);
    acc[7][0] = fmaf(a1.w, wv.x, acc[7][0]);
    acc[7][1] = fmaf(a1.w, wv.y, acc[7][1]);
    acc[7][2] = fmaf(a1.w, wv.z, acc[7][2]);
    acc[7][3] = fmaf(a1.w, wv.w, acc[7][3]);
}

// Grid: 1024 blocks = 2 (j) x 32 (f-tile of 256) x 16 (K-chunk s). Block = 256 (4 waves),
// 4 blocks/CU (LDS 36 KB). Wave w owns batches [w*8, w*8+8); lane owns 4 consecutive f.
// BOTH operands staged via __builtin_amdgcn_global_load_lds (16B DMA, no VGPR round trip,
// no scratch risk) into double-buffered LDS: wtile[2][16][256] + itile[2][16][32].
// DMA dest is wave-uniform row base (lane*16B fills one contiguous 1 KB row); global src
// is per-lane. Stage t+1 issued right after the barrier, consumed after a full compute
// phase -> HBM latency hidden. One __syncthreads per stage (its vmcnt(0) is the drain).
__global__ __launch_bounds__(256, 4) void gemm_partial(const float* __restrict__ in_t,
                                                       const float* __restrict__ wsm,
                                                       float* __restrict__ partial) {
    __shared__ float wtile[2][16][256];   // 32 KB
    __shared__ float itile[2][16][32];    //  4 KB

    int lin = blockIdx.x;
    int s   = lin & (NSPLIT - 1);
    int ft  = (lin >> 4) & 31;
    int j   = lin >> 9;
    int w    = __builtin_amdgcn_readfirstlane((int)(threadIdx.x >> 6));
    int lane = threadIdx.x & 63;
    int f0   = ft * 256 + lane * 4;
    int k0   = s * 512;

    // per-lane global sources for this wave's staging share
    const float* __restrict__ wsrc = wsm + ((size_t)j * 8192 + k0 + w) * 8192 + f0;
    const float* __restrict__ isrc = in_t + (size_t)(j * 8192 + k0) * 32 + w * 256 + lane * 4;

#define GLDS16(GP, LP)                                                          \
    __builtin_amdgcn_global_load_lds(                                           \
        (const __attribute__((address_space(1))) void*)(GP),                    \
        (__attribute__((address_space(3))) void*)(LP), 16, 0, 0)

    // DMA-issue one 16-row stage into buffer (T)&1. Rows w,w+4,w+8,w+12 per wave (ws);
    // waves 0-1 bring the 16x32 in_t slice (contiguous source).
#define STAGE_ISSUE(T)                                                          \
    do {                                                                        \
        int buf_ = (T) & 1;                                                     \
        const float* gp_ = wsrc + (size_t)(T) * 16 * 8192;                      \
        GLDS16(gp_,                     &wtile[buf_][w +  0][0]);               \
        GLDS16(gp_ + (size_t)4  * 8192, &wtile[buf_][w +  4][0]);               \
        GLDS16(gp_ + (size_t)8  * 8192, &wtile[buf_][w +  8][0]);               \
        GLDS16(gp_ + (size_t)12 * 8192, &wtile[buf_][w + 12][0]);               \
        if (w < 2) GLDS16(isrc + (T) * 512, &itile[buf_][w * 8][0]);            \
    } while (0)

    float acc[8][4];
#pragma unroll
    for (int b = 0; b < 8; ++b)
#pragma unroll
        for (int q = 0; q < 4; ++q) acc[b][q] = 0.f;

    STAGE_ISSUE(0);
    __syncthreads();          // vmcnt(0) drain -> buf0 resident

    int w8 = w * 8;
    int l4 = lane * 4;
    for (int t = 0; t < 32; ++t) {
        if (t + 1 < 32) STAGE_ISSUE(t + 1);    // in flight across this compute phase
        const float(*wt)[256] = wtile[t & 1];
        const float(*it)[32]  = itile[t & 1];
#pragma unroll 4
        for (int r = 0; r < 16; ++r) {
            float4 wv = *(const float4*)&wt[r][l4];
            float4 a0 = *(const float4*)&it[r][w8];
            float4 a1 = *(const float4*)&it[r][w8 + 4];
            fma_row(acc, a0, a1, wv);
        }
        __syncthreads();      // drains vmcnt -> buf (t+1) resident, readers of buf t done
    }
#undef STAGE_ISSUE
#undef GLDS16

    // partial[j][s][b][f]: coalesced float4 stores
    size_t pbase = ((size_t)((j * NSPLIT + s) * 32 + w8)) * 8192 + f0;
#pragma unroll
    for (int b = 0; b < 8; ++b)
        *(float4*)(partial + pbase + (size_t)b * 8192) = *(const float4*)acc[b];
}

__device__ __forceinline__ float sigmoidf_(float v) { return 1.f / (1.f + expf(-v)); }

// 131072 threads: tid -> (j, b, un)
__global__ __launch_bounds__(256) void epilogue(const float* __restrict__ partial,
                                                const float* __restrict__ cs,
                                                float* __restrict__ out) {
    int tid = blockIdx.x * 256 + threadIdx.x;
    int un  = tid & 2047;
    int b   = (tid >> 11) & 31;
    int j   = tid >> 16;

    float g4[4];
#pragma unroll
    for (int gate = 0; gate < 4; ++gate) {
        int f = gate * 2048 + un;
        float sum = 0.f;
#pragma unroll
        for (int s = 0; s < NSPLIT; ++s)
            sum += partial[((size_t)((j * NSPLIT + s) * 32 + b)) * 8192 + f];
        g4[gate] = sum;
    }
    float iv = sigmoidf_(g4[0]);
    float fv = sigmoidf_(g4[1]);
    float gv = tanhf(g4[2]);
    float ov = sigmoidf_(g4[3]);
    float ig = iv * gv;

#pragma unroll
    for (int kk = 0; kk < 4; ++kk) {
        float c_old = cs[((j * 4 + kk) * 32 + b) * 2048 + un];
        float c_new = fv * c_old + ig;
        float h     = ov * tanhf(c_new);
        out[393216 + ((j * 4 + kk) * 32 + b) * 2048 + un] = c_new;   // new_c
        if (kk == 0) {
            out[b * 4096 + j * 2048 + un] = h;                       // x_out
        }
        if (kk == j + 2) {
            // new_hs[jj][j][b][un] = h for jj in {0,1}
            out[131072 + ((0 * 2 + j) * 32 + b) * 2048 + un] = h;
            out[131072 + ((1 * 2 + j) * 32 + b) * 2048 + un] = h;
        }
    }
}

extern "C" void kernel_launch(void* const* d_in, const int* in_sizes, int n_in,
                              void* d_out, int out_size, void* d_ws, size_t ws_size,
                              hipStream_t stream) {
    const float* x   = (const float*)d_in[0];
    const float* hs  = (const float*)d_in[1];
    const float* cs  = (const float*)d_in[2];
    const float* wsm = (const float*)d_in[3];
    float* out = (float*)d_out;

    float* in_t    = (float*)d_ws;                                    // 2 MB
    float* partial = (float*)((char*)d_ws + (size_t)IN_T_ELEMS * 4);  // 33.5 MB

    transpose_in<<<524288 / 256, 256, 0, stream>>>(x, hs, in_t);
    gemm_partial<<<1024, 256, 0, stream>>>(in_t, wsm, partial);
    epilogue<<<131072 / 256, 256, 0, stream>>>(partial, cs, out);
}